// Round 13
// baseline (106.238 us; speedup 1.0000x reference)
//
#include <hip/hip_runtime.h>
#include <hip/hip_bf16.h>

typedef __attribute__((ext_vector_type(4)))  float f32x4;
typedef __attribute__((ext_vector_type(16))) float f32x16;
typedef __attribute__((ext_vector_type(8)))  short s16x8;
typedef __attribute__((ext_vector_type(4)))  unsigned int u32x4;

using bf16 = __hip_bfloat16;

#define DIMC   1024
#define NH     16
#define HD     64
#define SEQ    2048
#define NB     2
#define NROWS  (NB*SEQ)   // 4096
#define NQKV   1152       // 1024 q + 64 k + 64 v
#define QSCL   0.18033688f   // 1/sqrt(64) * log2(e), folded into Q at rope time

// ---------------- fused cast fp32 -> bf16 for all 5 inputs ----------------
// Wo is pre-multiplied by norm_w[d] (rmsnorm folds into Wo's columns).
__global__ __launch_bounds__(256) void cast_all_kernel(const float* __restrict__ x,
                                                       const float* __restrict__ wq,
                                                       const float* __restrict__ wk,
                                                       const float* __restrict__ wv,
                                                       const float* __restrict__ wo,
                                                       const float* __restrict__ nw,
                                                       bf16* __restrict__ xbf,
                                                       bf16* __restrict__ wqkv,
                                                       bf16* __restrict__ wob) {
  int i = blockIdx.x * blockDim.x + threadIdx.x;   // 4-elem group id
  if (i >= 1343488) {                   // Wo segment (with norm_w fold)
    int j = i - 1343488;
    const float* s = wo + (size_t)j * 4;
    bf16* d = wob + (size_t)j * 4;
    int d0 = (j * 4) & 1023;
    float4 v = *(const float4*)s;
    float4 g = *(const float4*)(nw + d0);
    d[0] = __float2bfloat16(v.x * g.x);
    d[1] = __float2bfloat16(v.y * g.y);
    d[2] = __float2bfloat16(v.z * g.z);
    d[3] = __float2bfloat16(v.w * g.w);
    return;
  }
  const float* s;
  bf16* d;
  if (i < 1048576)      { s = x  + (size_t)i * 4;                 d = xbf + (size_t)i * 4; }
  else if (i < 1310720) { int j = i - 1048576; s = wq + (size_t)j * 4; d = wqkv + (size_t)j * 4; }
  else if (i < 1327104) { int j = i - 1310720; s = wk + (size_t)j * 4; d = wqkv + (size_t)1024 * 1024 + (size_t)j * 4; }
  else                  { int j = i - 1327104; s = wv + (size_t)j * 4; d = wqkv + (size_t)1088 * 1024 + (size_t)j * 4; }
  float4 v = *(const float4*)s;
  d[0] = __float2bfloat16(v.x);
  d[1] = __float2bfloat16(v.y);
  d[2] = __float2bfloat16(v.z);
  d[3] = __float2bfloat16(v.w);
}

// ---------------- bf16 GEMM v2: 2-phase pipelined, counted vmcnt ----------
// C[M][N] = A[M][K] * B[N][K]^T. Tile 128x64, BK=64, double-buffered LDS.
// Per k-step: issue next tile's 6 global_load_lds, then s_waitcnt vmcnt(6)
// (prior tile drained, prefetch stays in flight) + raw s_barrier, compute,
// barrier. 1-D grid with bijective XCD swizzle (nwg % 8 == 0).
// SCALE: fused rmsnorm from ssq. OUTBF: bf16 out.
template <bool SCALE, bool OUTBF>
__global__ __launch_bounds__(256) void gemm_bt(const bf16* __restrict__ A,
                                               const bf16* __restrict__ Bm,
                                               void* __restrict__ Cv,
                                               const float* __restrict__ ssq,
                                               int M, int N, int K) {
  __shared__ bf16 lA[2][128 * 64];
  __shared__ bf16 lB[2][64 * 64];
  __shared__ float rms_l[128];
  const int tid = threadIdx.x;
  const int w = tid >> 6, l = tid & 63;
  const int lg = l >> 4, ln = l & 15;
  const int wr = w >> 1, wc = w & 1;

  // XCD-aware swizzle: consecutive swz-blocks (same B panel) land on one XCD
  const int nm = M >> 7;
  const int nwg = gridDim.x;
  const int bid = blockIdx.x;
  const int swz = (bid & 7) * (nwg >> 3) + (bid >> 3);
  const int m0 = (swz % nm) * 128, n0 = (swz / nm) * 64;

  if (SCALE && tid < 128) {
    const float4* s4 = (const float4*)(ssq + (size_t)(m0 + tid) * 16);
    float4 a = s4[0], b = s4[1], c = s4[2], d = s4[3];
    float tot = (a.x + a.y + a.z + a.w) + (b.x + b.y + b.z + b.w) +
                (c.x + c.y + c.z + c.w) + (d.x + d.y + d.z + d.w);
    rms_l[tid] = rsqrtf(tot * (1.0f / 1024.0f) + 1e-6f);
  }

  auto stage = [&](int buf, int k0) {
#pragma unroll
    for (int it = 0; it < 4; ++it) {
      int c = tid + it * 256;
      int row = c >> 3, col = (c & 7) * 8;
      __builtin_amdgcn_global_load_lds(
          (const __attribute__((address_space(1))) void*)(A + (size_t)(m0 + row) * K + k0 + col),
          (__attribute__((address_space(3))) void*)(&lA[buf][c * 8]), 16, 0, 0);
    }
#pragma unroll
    for (int it = 0; it < 2; ++it) {
      int c = tid + it * 256;
      int row = c >> 3, col = (c & 7) * 8;
      __builtin_amdgcn_global_load_lds(
          (const __attribute__((address_space(1))) void*)(Bm + (size_t)(n0 + row) * K + k0 + col),
          (__attribute__((address_space(3))) void*)(&lB[buf][c * 8]), 16, 0, 0);
    }
  };

  f32x4 acc[4][2] = {};

  stage(0, 0);
  int cur = 0;
  const int NS = K >> 6;                // 16 for K=1024
  for (int s = 0; s < NS; ++s) {
    if (s + 1 < NS) {
      stage(cur ^ 1, (s + 1) << 6);     // prefetch next tile (stays in flight)
      asm volatile("s_waitcnt vmcnt(6)");   // drain only current tile's loads
    } else {
      asm volatile("s_waitcnt vmcnt(0)");
    }
    __builtin_amdgcn_s_barrier();
    __builtin_amdgcn_sched_barrier(0);
#pragma unroll
    for (int ks = 0; ks < 2; ++ks) {
      s16x8 af[4], bfr[2];
#pragma unroll
      for (int m = 0; m < 4; ++m)
        af[m] = *(const s16x8*)(&lA[cur][(wr * 64 + m * 16 + ln) * 64 + ks * 32 + lg * 8]);
#pragma unroll
      for (int n = 0; n < 2; ++n)
        bfr[n] = *(const s16x8*)(&lB[cur][(wc * 32 + n * 16 + ln) * 64 + ks * 32 + lg * 8]);
#pragma unroll
      for (int m = 0; m < 4; ++m)
#pragma unroll
        for (int n = 0; n < 2; ++n)
          acc[m][n] = __builtin_amdgcn_mfma_f32_16x16x32_bf16(af[m], bfr[n], acc[m][n], 0, 0, 0);
    }
    __builtin_amdgcn_sched_barrier(0);
    __builtin_amdgcn_s_barrier();
    cur ^= 1;
  }

  for (int m = 0; m < 4; ++m)
    for (int r = 0; r < 4; ++r) {
      int lrow = wr * 64 + m * 16 + lg * 4 + r;
      int grow = m0 + lrow;
      float sc = SCALE ? rms_l[lrow] : 1.0f;
      for (int n = 0; n < 2; ++n) {
        float v = SCALE ? acc[m][n][r] * sc : acc[m][n][r];
        size_t idx = (size_t)grow * N + n0 + wc * 32 + n * 16 + ln;
        if (OUTBF) ((bf16*)Cv)[idx] = __float2bfloat16(v);
        else       ((float*)Cv)[idx] = v;
      }
    }
}

// ---------------- RoPE + fragment-major repack (Y is bf16) ---------------
//   QF[b][h][qt][ks][lane][8] : lane=(hi*32+ql) holds Q[b,h,qt*32+ql][ks*16+hi*8+j]
//   KF[b][t][ks][lane][8]     : K[b, t*32+ql][ks*16+hi*8+j]
//   VF[b][t][c][dt][lane][8]  : V[b, t*32+c*16+hi*8+j][dt*32+ql]
__global__ __launch_bounds__(256) void rope_kernel(const bf16* __restrict__ Y,
                                                   bf16* __restrict__ QF,
                                                   bf16* __restrict__ KF,
                                                   bf16* __restrict__ VF) {
  const int r = blockIdx.x;             // 0..4095
  const int b = r >> 11, s = r & 2047;
  const int qt = s >> 5, ql = s & 31;
  const bf16* y = Y + (size_t)r * NQKV;
  for (int t = threadIdx.x; t < 576; t += blockDim.x) {
    if (t < 512) {                      // q pairs: h = t/32, i = t%32
      int h = t >> 5, i = t & 31;
      float x1 = __bfloat162float(y[h * 64 + 2 * i]);
      float x2 = __bfloat162float(y[h * 64 + 2 * i + 1]);
      float fr = expf(-(float)i * (9.210340371976184f / 32.0f)); // theta^(-i/32)
      float sn, cs;
      sincosf((float)s * fr, &sn, &cs);
      int f = 2 * i;
      int ks = f >> 4, hi = (f >> 3) & 1, j = f & 7;
      bf16* q = QF + ((size_t)((((b * NH + h) * 64 + qt) * 4 + ks) * 64 + hi * 32 + ql)) * 8 + j;
      q[0] = __float2bfloat16((x1 * cs - x2 * sn) * QSCL);
      q[1] = __float2bfloat16((x1 * sn + x2 * cs) * QSCL);
    } else if (t < 544) {               // k pairs
      int i = t - 512;
      float x1 = __bfloat162float(y[1024 + 2 * i]);
      float x2 = __bfloat162float(y[1024 + 2 * i + 1]);
      float fr = expf(-(float)i * (9.210340371976184f / 32.0f));
      float sn, cs;
      sincosf((float)s * fr, &sn, &cs);
      int f = 2 * i;
      int ks = f >> 4, hi = (f >> 3) & 1, j = f & 7;
      bf16* k = KF + ((size_t)(((b * 64 + qt) * 4 + ks) * 64 + hi * 32 + ql)) * 8 + j;
      k[0] = __float2bfloat16(x1 * cs - x2 * sn);
      k[1] = __float2bfloat16(x1 * sn + x2 * cs);
    } else {                            // v: d0 = 2i, 2i+1
      int i = t - 544;
      int d0 = 2 * i;
      int c = (s >> 4) & 1, hv = (s >> 3) & 1, jv = s & 7;
      int dt = d0 >> 5;
      bf16* p0 = VF + ((size_t)((((b * 64 + qt) * 2 + c) * 2 + dt) * 64 + hv * 32 + (d0 & 31))) * 8 + jv;
      p0[0] = y[1088 + d0];
      p0[8] = y[1088 + d0 + 1];
    }
  }
}

// ---- cross-lane helpers (gfx950) ----
static __device__ __forceinline__ unsigned cvt_pk_bf16(float lo, float hi) {
  unsigned r;
  asm("v_cvt_pk_bf16_f32 %0, %1, %2" : "=v"(r) : "v"(lo), "v"(hi));
  return r;
}
static __device__ __forceinline__ void pl32_swap(unsigned& x, unsigned& y) {
  asm("v_permlane32_swap_b32 %0, %1" : "+v"(x), "+v"(y));
}

// ---------------- Flash attention v12 (2 heads/wave, KV register-shared) ----
// (unchanged from round 12 — best-measured attention structure)
__global__ __launch_bounds__(256, 2) void attn12_kernel(const bf16* __restrict__ QF,
                                                        const bf16* __restrict__ KF,
                                                        const bf16* __restrict__ VF,
                                                        bf16* __restrict__ Nb,
                                                        float* __restrict__ ssq) {
  __shared__ float cb[2][64][66];
  const int bid = blockIdx.x;
  const int fold = bid >> 4;            // 0..31 (slowest)
  const int hp = (bid >> 1) & 7;
  const int b  = bid & 1;
  const int w  = threadIdx.x >> 6;      // wave 0..3 (kv-split)
  const int l  = threadIdx.x & 63;
  const int ql = l & 31, hi = l >> 5;
  const int h0 = hp * 2, h1 = hp * 2 + 1;

  auto run_qtile = [&](int qt) {
    const bf16* qp0 = QF + ((size_t)((b * NH + h0) * 64 + qt) * 256 + l) * 8;
    const bf16* qp1 = QF + ((size_t)((b * NH + h1) * 64 + qt) * 256 + l) * 8;
    s16x8 qf0[4], qf1[4];
#pragma unroll
    for (int ks = 0; ks < 4; ++ks) {
      qf0[ks] = *(const s16x8*)(qp0 + ks * 512);
      qf1[ks] = *(const s16x8*)(qp1 + ks * 512);
    }

    const bf16* kp = KF + ((size_t)(b * 64 + w) * 256 + l) * 8;
    const bf16* vp = VF + ((size_t)(b * 64 + w) * 256 + l) * 8;

    f32x16 ot0[2] = {}, ot1[2] = {};
    float ls0 = 0.f, ls1 = 0.f;

    auto loadK = [&](s16x8 (&kf)[4]) {
#pragma unroll
      for (int ks = 0; ks < 4; ++ks) kf[ks] = *(const s16x8*)(kp + ks * 512);
      kp += 4 * 1024 * 2;               // 4 tiles x 2048 elems
    };

    auto softmax_pv = [&](const f32x16& sa, const f32x16& sb, bool diag,
                          float& ls, f32x16 (&ot)[2], s16x8 (&vf)[4]) {
      float p[16];
      if (diag) {
#pragma unroll
        for (int r = 0; r < 16; ++r) {
          const int cr = (r & 3) + 8 * (r >> 2);
          p[r] = (cr + 4 * hi > ql) ? 0.f : exp2f(sa[r] + sb[r]);
        }
      } else {
#pragma unroll
        for (int r = 0; r < 16; ++r) p[r] = exp2f(sa[r] + sb[r]);
      }
      float t8[8];
#pragma unroll
      for (int r = 0; r < 8; ++r) t8[r] = p[2 * r] + p[2 * r + 1];
#pragma unroll
      for (int r = 0; r < 4; ++r) t8[r] = t8[r] + t8[r + 4];
      float rs = (t8[0] + t8[2]) + (t8[1] + t8[3]);
      rs += __shfl_xor(rs, 32);
      ls += rs;
#pragma unroll
      for (int c = 0; c < 2; ++c) {
        unsigned w0 = cvt_pk_bf16(p[c * 8 + 0], p[c * 8 + 1]);
        unsigned w2 = cvt_pk_bf16(p[c * 8 + 4], p[c * 8 + 5]);
        unsigned w1 = cvt_pk_bf16(p[c * 8 + 2], p[c * 8 + 3]);
        unsigned w3 = cvt_pk_bf16(p[c * 8 + 6], p[c * 8 + 7]);
        pl32_swap(w0, w2);
        pl32_swap(w1, w3);
        u32x4 pu = {w0, w1, w2, w3};
        s16x8 pb = *(s16x8*)&pu;
        __builtin_amdgcn_s_setprio(1);
#pragma unroll
        for (int dt = 0; dt < 2; ++dt)
          ot[dt] = __builtin_amdgcn_mfma_f32_32x32x16_bf16(vf[c * 2 + dt], pb, ot[dt], 0, 0, 0);
        __builtin_amdgcn_s_setprio(0);
      }
    };

    auto compute = [&](int t, s16x8 (&kf)[4]) {
      s16x8 vf[4];
#pragma unroll
      for (int j = 0; j < 4; ++j) vf[j] = *(const s16x8*)(vp + j * 512);
      vp += 4 * 1024 * 2;
      const bool diag = (t == qt);
      f32x16 s0a = {}, s0b = {}, s1a = {}, s1b = {};
      __builtin_amdgcn_s_setprio(1);
      s0a = __builtin_amdgcn_mfma_f32_32x32x16_bf16(kf[0], qf0[0], s0a, 0, 0, 0);
      s1a = __builtin_amdgcn_mfma_f32_32x32x16_bf16(kf[0], qf1[0], s1a, 0, 0, 0);
      s0b = __builtin_amdgcn_mfma_f32_32x32x16_bf16(kf[2], qf0[2], s0b, 0, 0, 0);
      s1b = __builtin_amdgcn_mfma_f32_32x32x16_bf16(kf[2], qf1[2], s1b, 0, 0, 0);
      s0a = __builtin_amdgcn_mfma_f32_32x32x16_bf16(kf[1], qf0[1], s0a, 0, 0, 0);
      s1a = __builtin_amdgcn_mfma_f32_32x32x16_bf16(kf[1], qf1[1], s1a, 0, 0, 0);
      s0b = __builtin_amdgcn_mfma_f32_32x32x16_bf16(kf[3], qf0[3], s0b, 0, 0, 0);
      s1b = __builtin_amdgcn_mfma_f32_32x32x16_bf16(kf[3], qf1[3], s1b, 0, 0, 0);
      __builtin_amdgcn_s_setprio(0);
      softmax_pv(s0a, s0b, diag, ls0, ot0, vf);
      softmax_pv(s1a, s1b, diag, ls1, ot1, vf);
    };

    // main loop: K prefetched 1 tile ahead (named buffers), V in compute
    s16x8 kA[4], kB[4];
    int t = w;
    if (t <= qt) {
      loadK(kA);
      while (true) {
        if (t + 4 <= qt) loadK(kB);
        compute(t, kA);
        t += 4;
        if (t > qt) break;
        if (t + 4 <= qt) loadK(kA);
        compute(t, kB);
        t += 4;
        if (t > qt) break;
      }
    }

    // ---- LDS tree combine (pure sums, both heads) ----
    auto dumpLDS = [&](int slot) {
      float* dst = &cb[slot][l][0];
#pragma unroll
      for (int r = 0; r < 16; ++r) {
        dst[r]      = ot0[0][r];
        dst[16 + r] = ot0[1][r];
        dst[32 + r] = ot1[0][r];
        dst[48 + r] = ot1[1][r];
      }
      dst[64] = ls0; dst[65] = ls1;
    };
    auto mergeLDS = [&](int slot) {
      const float* src = &cb[slot][l][0];
#pragma unroll
      for (int r = 0; r < 16; ++r) {
        ot0[0][r] += src[r];
        ot0[1][r] += src[16 + r];
        ot1[0][r] += src[32 + r];
        ot1[1][r] += src[48 + r];
      }
      ls0 += src[64]; ls1 += src[65];
    };

    __syncthreads();                    // protect cb reuse across phases
    if (w == 1) dumpLDS(0);
    if (w == 3) dumpLDS(1);
    __syncthreads();
    if (w == 0) mergeLDS(0);
    if (w == 2) mergeLDS(1);
    __syncthreads();
    if (w == 2) dumpLDS(0);
    __syncthreads();
    if (w == 0) {
      mergeLDS(0);
      const int rowg = b * SEQ + qt * 32 + ql;
      {
        float inv = 1.0f / ls0;
        float sq = 0.f;
        bf16* nb = Nb + (size_t)rowg * DIMC + h0 * HD;
#pragma unroll
        for (int dt = 0; dt < 2; ++dt)
#pragma unroll
          for (int rq = 0; rq < 4; ++rq) {
            float o0 = ot0[dt][4 * rq + 0] * inv, o1 = ot0[dt][4 * rq + 1] * inv;
            float o2 = ot0[dt][4 * rq + 2] * inv, o3 = ot0[dt][4 * rq + 3] * inv;
            sq += o0 * o0 + o1 * o1 + o2 * o2 + o3 * o3;
            uint2 pk = { cvt_pk_bf16(o0, o1), cvt_pk_bf16(o2, o3) };
            *(uint2*)(nb + dt * 32 + rq * 8 + 4 * hi) = pk;
          }
        sq += __shfl_xor(sq, 32);
        if (hi == 0) ssq[rowg * 16 + h0] = sq;
      }
      {
        float inv = 1.0f / ls1;
        float sq = 0.f;
        bf16* nb = Nb + (size_t)rowg * DIMC + h1 * HD;
#pragma unroll
        for (int dt = 0; dt < 2; ++dt)
#pragma unroll
          for (int rq = 0; rq < 4; ++rq) {
            float o0 = ot1[dt][4 * rq + 0] * inv, o1 = ot1[dt][4 * rq + 1] * inv;
            float o2 = ot1[dt][4 * rq + 2] * inv, o3 = ot1[dt][4 * rq + 3] * inv;
            sq += o0 * o0 + o1 * o1 + o2 * o2 + o3 * o3;
            uint2 pk = { cvt_pk_bf16(o0, o1), cvt_pk_bf16(o2, o3) };
            *(uint2*)(nb + dt * 32 + rq * 8 + 4 * hi) = pk;
          }
        sq += __shfl_xor(sq, 32);
        if (hi == 0) ssq[rowg * 16 + h1] = sq;
      }
    }
  };

  run_qtile(fold);                      // light q-tile
  run_qtile(63 - fold);                 // heavy q-tile (sum = const 65 tiles)
}

// ---------------- launch ----------------
extern "C" void kernel_launch(void* const* d_in, const int* in_sizes, int n_in,
                              void* d_out, int out_size, void* d_ws, size_t ws_size,
                              hipStream_t stream) {
  const float* x      = (const float*)d_in[0];
  const float* Wq     = (const float*)d_in[1];
  const float* Wk     = (const float*)d_in[2];
  const float* Wv     = (const float*)d_in[3];
  const float* Wo     = (const float*)d_in[4];
  const float* norm_w = (const float*)d_in[5];

  size_t off = 0;
  auto alloc = [&](size_t bytes) {
    void* p = (char*)d_ws + off;
    off += (bytes + 255) & ~(size_t)255;
    return p;
  };
  bf16*  Xbf  = (bf16*)alloc((size_t)NROWS * DIMC * 2);
  bf16*  Wqkv = (bf16*)alloc((size_t)NQKV * DIMC * 2);
  bf16*  Wob  = (bf16*)alloc((size_t)DIMC * DIMC * 2);
  bf16*  Yb   = (bf16*)alloc((size_t)NROWS * NQKV * 2);
  bf16*  QF   = (bf16*)alloc((size_t)NB * NH * 64 * 4 * 64 * 8 * 2);   // 8 MB
  bf16*  KF   = (bf16*)alloc((size_t)NB * 64 * 4 * 64 * 8 * 2);        // 1 MB
  bf16*  VF   = (bf16*)alloc((size_t)NB * 64 * 4 * 64 * 8 * 2);        // 1 MB
  bf16*  Nb   = (bf16*)alloc((size_t)NROWS * DIMC * 2);
  float* ssq  = (float*)alloc((size_t)NROWS * 16 * 4);

  // fused input casts (norm_w folded into Wo)
  cast_all_kernel<<<6272, 256, 0, stream>>>(x, Wq, Wk, Wv, Wo, norm_w, Xbf, Wqkv, Wob);

  // QKV projection: Yb[4096][1152] (bf16) = Xbf @ Wqkv^T  (2-phase, 576 blocks)
  gemm_bt<false, true><<<(NROWS / 128) * (NQKV / 64), 256, 0, stream>>>(
      Xbf, Wqkv, Yb, nullptr, NROWS, NQKV, DIMC);

  // RoPE + fragment-major repack
  rope_kernel<<<NROWS, 256, 0, stream>>>(Yb, QF, KF, VF);

  // attention v12 (2 heads/wave, KV register-shared, fold-balanced)
  attn12_kernel<<<NB * 8 * 32, 256, 0, stream>>>(QF, KF, VF, Nb, ssq);

  // output projection with fused rms (computed in-block from ssq) into d_out
  gemm_bt<true, false><<<(NROWS / 128) * (DIMC / 64), 256, 0, stream>>>(
      Nb, Wob, (float*)d_out, ssq, NROWS, DIMC, DIMC);
}